// Round 3
// baseline (1223.639 us; speedup 1.0000x reference)
//
#include <hip/hip_runtime.h>
#include <stdint.h>

#define CDIM   256
#define NPIX   65536
#define NBATCH 8
#define WCOLS  64
#define NTILES 1024                       // tiles per batch (NPIX/WCOLS)
#define TPB    16                         // tiles per block
#define NBLOCKS (NBATCH * NTILES / TPB)   // 512
#define KTHRESH 0.01

// workspace layout (float indices)
#define WS_DELTA 0        // 256 floats: normalize(c1)-normalize(c0)
#define WS_CENT  256      // 512 floats: current raw centers [K][C]
#define WS_T     768      // 2048 floats: per-batch totals  T[b][c]
#define WS_S1    2816     // 2048 floats: per-batch label-1 sums S1[b][c]
#define WS_CNT   4864     // 8 uints: per-batch label-1 counts
#define WS_DONE  4872     // 1 int: convergence flag

// output layout (floats): centers[2*256] | labels[8*65536] | onehot[8*65536*2] | cur_dist
#define OUT_LABELS 512
#define OUT_ONEHOT (512 + NBATCH * NPIX)
#define OUT_CDIST  (512 + NBATCH * NPIX + 2 * NBATCH * NPIX)

__device__ __forceinline__ double block_reduce(double v, double* sh) {
  const int t = threadIdx.x;
  #pragma unroll
  for (int off = 32; off > 0; off >>= 1) v += __shfl_down(v, off, 64);
  __syncthreads();
  if ((t & 63) == 0) sh[t >> 6] = v;
  __syncthreads();
  return sh[0] + sh[1] + sh[2] + sh[3];
}

__device__ __forceinline__ void block_reduce4(double v[4], double* sh) {
  const int t = threadIdx.x;
  #pragma unroll
  for (int off = 32; off > 0; off >>= 1) {
    v[0] += __shfl_down(v[0], off, 64);
    v[1] += __shfl_down(v[1], off, 64);
    v[2] += __shfl_down(v[2], off, 64);
    v[3] += __shfl_down(v[3], off, 64);
  }
  __syncthreads();
  if ((t & 63) == 0) {
    const int w = t >> 6;
    sh[w] = v[0]; sh[4 + w] = v[1]; sh[8 + w] = v[2]; sh[12 + w] = v[3];
  }
  __syncthreads();
  #pragma unroll
  for (int k = 0; k < 4; ++k) v[k] = sh[4 * k] + sh[4 * k + 1] + sh[4 * k + 2] + sh[4 * k + 3];
}

__global__ __launch_bounds__(256) void init_kernel(const float* __restrict__ cinit,
                                                   float* __restrict__ ws) {
  __shared__ double sh[16];
  const int t = threadIdx.x;
  for (int i = t; i < NBATCH * CDIM; i += 256) { ws[WS_T + i] = 0.f; ws[WS_S1 + i] = 0.f; }
  if (t < NBATCH) ((unsigned int*)(ws + WS_CNT))[t] = 0u;
  if (t == 0) ((int*)(ws + WS_DONE))[0] = 0;
  const float c0f = cinit[t], c1f = cinit[CDIM + t];
  ws[WS_CENT + t] = c0f;
  ws[WS_CENT + CDIM + t] = c1f;
  const double c0 = (double)c0f, c1 = (double)c1f;
  double n0 = sqrt(block_reduce(c0 * c0, sh));
  double n1 = sqrt(block_reduce(c1 * c1, sh));
  n0 = fmax(n0, 1e-12); n1 = fmax(n1, 1e-12);
  ws[WS_DELTA + t] = (float)(c1 / n1) - (float)(c0 / n0);
}

// Register-resident streaming pass. 512 blocks x 16 tiles. Lane (w,l) owns
// channels [w*64+(l>>4)*16, +16) x columns [(l&15)*4, +4) of each tile, held
// as 16 float4 in VGPRs (double-buffered A/B). Labels via shfl + tiny LDS
// exchange (1 barrier/tile); masked sums accumulate in registers across all
// 16 tiles; one shfl-reduce + 256 fp32 atomics per block at the end.
__global__ __launch_bounds__(256, 2) void pass_kernel(const float* __restrict__ F,
                                                      float* __restrict__ ws,
                                                      float* __restrict__ out,
                                                      int iter) {
  if (iter > 0 && ((const volatile int*)(ws + WS_DONE))[0] != 0) return;

  __shared__ double pd[2][4][16][5];   // [parity][wave][colgrp][4 used + pad]

  const int t    = threadIdx.x;
  const int w    = t >> 6;             // wave 0..3
  const int l    = t & 63;
  const int cg   = l & 15;             // column group: cols cg*4 .. cg*4+3
  const int rgrp = l >> 4;             // channel sub-block within wave
  const int b    = blockIdx.x >> 6;    // 64 blocks per batch
  const int tile0 = (blockIdx.x & 63) * TPB;
  const int cbase = w * 64 + rgrp * 16;   // lane's 16 channels

  float dreg[16];
  #pragma unroll
  for (int r = 0; r < 16; ++r) dreg[r] = ws[WS_DELTA + cbase + r];

  const float* Fb = F + (size_t)b * CDIM * NPIX + (size_t)cbase * NPIX + (size_t)cg * 4;

  float4 A[16], Bv[16];
  float s1[16], tv[16];
  #pragma unroll
  for (int r = 0; r < 16; ++r) { s1[r] = 0.f; tv[r] = 0.f; }
  unsigned cnt = 0;

  auto load_tile = [&](float4* buf, int tile) {
    const float* p = Fb + (size_t)tile * WCOLS;
    #pragma unroll
    for (int r = 0; r < 16; ++r)
      buf[r] = *(const float4*)(p + (size_t)r * NPIX);
  };

  auto process = [&](const float4* V, int i) {
    // phase 1: fp64 partial dots for this lane's 4 columns over its 16 channels
    double d0 = 0.0, d1 = 0.0, d2 = 0.0, d3 = 0.0;
    #pragma unroll
    for (int r = 0; r < 16; ++r) {
      const double dc = (double)dreg[r];
      d0 = fma(dc, (double)V[r].x, d0);
      d1 = fma(dc, (double)V[r].y, d1);
      d2 = fma(dc, (double)V[r].z, d2);
      d3 = fma(dc, (double)V[r].w, d3);
    }
    // reduce over the 4 channel sub-blocks within the wave (lanes cg, cg+16, ...)
    d0 += __shfl_xor(d0, 16, 64); d0 += __shfl_xor(d0, 32, 64);
    d1 += __shfl_xor(d1, 16, 64); d1 += __shfl_xor(d1, 32, 64);
    d2 += __shfl_xor(d2, 16, 64); d2 += __shfl_xor(d2, 32, 64);
    d3 += __shfl_xor(d3, 16, 64); d3 += __shfl_xor(d3, 32, 64);
    const int par = i & 1;
    if (rgrp == 0) {
      pd[par][w][cg][0] = d0; pd[par][w][cg][1] = d1;
      pd[par][w][cg][2] = d2; pd[par][w][cg][3] = d3;
    }
    __syncthreads();
    const double f0 = pd[par][0][cg][0] + pd[par][1][cg][0] + pd[par][2][cg][0] + pd[par][3][cg][0];
    const double f1 = pd[par][0][cg][1] + pd[par][1][cg][1] + pd[par][2][cg][1] + pd[par][3][cg][1];
    const double f2 = pd[par][0][cg][2] + pd[par][1][cg][2] + pd[par][2][cg][2] + pd[par][3][cg][2];
    const double f3 = pd[par][0][cg][3] + pd[par][1][cg][3] + pd[par][2][cg][3] + pd[par][3][cg][3];
    const float m0 = f0 > 0.0 ? 1.f : 0.f;
    const float m1 = f1 > 0.0 ? 1.f : 0.f;
    const float m2 = f2 > 0.0 ? 1.f : 0.f;
    const float m3 = f3 > 0.0 ? 1.f : 0.f;

    if (w == 0 && rgrp == 0) {
      const int gi = b * NPIX + (tile0 + i) * WCOLS + cg * 4;
      *(float4*)(out + OUT_LABELS + gi) = make_float4(m0, m1, m2, m3);
      float4* oh = (float4*)(out + OUT_ONEHOT + 2 * (size_t)gi);
      oh[0] = make_float4(1.f - m0, m0, 1.f - m1, m1);
      oh[1] = make_float4(1.f - m2, m2, 1.f - m3, m3);
      cnt += (unsigned)(m0 + m1 + m2 + m3);
    }

    // phase 2: masked accumulation on register-held values
    #pragma unroll
    for (int r = 0; r < 16; ++r) {
      const float4 v = V[r];
      float a = fmaf(m0, v.x, s1[r]);
      a = fmaf(m1, v.y, a);
      a = fmaf(m2, v.z, a);
      s1[r] = fmaf(m3, v.w, a);
      tv[r] += (v.x + v.y) + (v.z + v.w);
    }
  };

  load_tile(A, tile0);
  for (int i = 0; i < TPB; i += 2) {
    load_tile(Bv, tile0 + i + 1);
    process(A, i);
    if (i + 2 < TPB) load_tile(A, tile0 + i + 2);
    process(Bv, i + 1);
  }

  // flush: reduce across the 16 lanes (cg) that share this channel set
  #pragma unroll
  for (int r = 0; r < 16; ++r) {
    #pragma unroll
    for (int m = 1; m < 16; m <<= 1) {
      s1[r] += __shfl_xor(s1[r], m, 64);
      tv[r] += __shfl_xor(tv[r], m, 64);
    }
  }
  if (cg == 0) {
    #pragma unroll
    for (int r = 0; r < 16; ++r) {
      unsafeAtomicAdd(&ws[WS_S1 + b * CDIM + cbase + r], s1[r]);
      if (iter == 0) unsafeAtomicAdd(&ws[WS_T + b * CDIM + cbase + r], tv[r]);
    }
  }
  if (w == 0 && rgrp == 0) {
    cnt += __shfl_down(cnt, 8, 16);
    cnt += __shfl_down(cnt, 4, 16);
    cnt += __shfl_down(cnt, 2, 16);
    cnt += __shfl_down(cnt, 1, 16);
    if (cg == 0) atomicAdd(&((unsigned int*)(ws + WS_CNT))[b], cnt);
  }
}

__global__ __launch_bounds__(256) void finalize_kernel(float* __restrict__ ws,
                                                       float* __restrict__ out) {
  __shared__ double sh[16];
  const int t = threadIdx.x;
  if (((const volatile int*)(ws + WS_DONE))[0] != 0) return;  // frozen: keep prior outputs

  const double cold0 = (double)ws[WS_CENT + t];
  const double cold1 = (double)ws[WS_CENT + CDIM + t];
  const double normc0 = sqrt(block_reduce(cold0 * cold0, sh));
  const double normc1 = sqrt(block_reduce(cold1 * cold1, sh));

  double acc0 = 0.0, acc1 = 0.0, cdsum = 0.0;
  for (int b = 0; b < NBATCH; ++b) {
    const double s1v  = (double)ws[WS_S1 + b * CDIM + t];
    const double totv = (double)ws[WS_T  + b * CDIM + t];
    const double c1n  = (double)((unsigned int*)(ws + WS_CNT))[b];
    const double ci1  = s1v / (c1n + 1.0);
    const double ci0  = (totv - s1v) / ((double)NPIX - c1n + 1.0);
    acc0 += ci0; acc1 += ci1;
    double v[4] = {ci0 * cold0, ci0 * ci0, ci1 * cold1, ci1 * ci1};
    block_reduce4(v, sh);
    const double den0 = fmax(sqrt(v[1]) * normc0, 1e-8);
    const double den1 = fmax(sqrt(v[3]) * normc1, 1e-8);
    cdsum += 0.5 * (v[0] / den0 + v[2] / den1);
  }
  const double curdist = cdsum / (double)NBATCH;
  const float nc0f = (float)(acc0 / (double)NBATCH);
  const float nc1f = (float)(acc1 / (double)NBATCH);

  ws[WS_CENT + t] = nc0f;
  ws[WS_CENT + CDIM + t] = nc1f;
  out[t] = nc0f;
  out[CDIM + t] = nc1f;
  if (t == 0) out[OUT_CDIST] = (float)curdist;

  double m0 = sqrt(block_reduce((double)nc0f * (double)nc0f, sh));
  double m1 = sqrt(block_reduce((double)nc1f * (double)nc1f, sh));
  m0 = fmax(m0, 1e-12); m1 = fmax(m1, 1e-12);
  ws[WS_DELTA + t] = (float)((double)nc1f / m1) - (float)((double)nc0f / m0);

  __syncthreads();
  for (int i = t; i < NBATCH * CDIM; i += 256) ws[WS_S1 + i] = 0.f;
  if (t < NBATCH) ((unsigned int*)(ws + WS_CNT))[t] = 0u;
  if (t == 0) ((int*)(ws + WS_DONE))[0] = (curdist < KTHRESH) ? 1 : 0;
}

extern "C" void kernel_launch(void* const* d_in, const int* in_sizes, int n_in,
                              void* d_out, int out_size, void* d_ws, size_t ws_size,
                              hipStream_t stream) {
  const float* F     = (const float*)d_in[0];
  const float* cinit = (const float*)d_in[1];
  float* out = (float*)d_out;
  float* ws  = (float*)d_ws;

  init_kernel<<<1, 256, 0, stream>>>(cinit, ws);
  for (int iter = 0; iter < 3; ++iter) {
    pass_kernel<<<NBLOCKS, 256, 0, stream>>>(F, ws, out, iter);
    finalize_kernel<<<1, 256, 0, stream>>>(ws, out);
  }
}